// Round 5
// baseline (780.241 us; speedup 1.0000x reference)
//
#include <hip/hip_runtime.h>

// NLBlock fused pipeline for MI355X (gfx950). ALL I/O IS FP32 (per reference).
// Internally: bf16 MFMA GEMMs; split-precision (hi/lo bf16) for x,lfb,th_w,ph_w,
// theta,phi so the x32-scaled softmax logits stay accurate.
// GEMM form: C[m][n] = sum_k A[m][k]*B[n][k] (+bias). 128x128x64 tile, 4 waves.
// R5: staging via __builtin_amdgcn_global_load_lds width=16 (m97 recipe),
// replacing R4's register-prefetch + ds_write (m93 recipe). One variable.

#define BM 128
#define BN 128
#define BK 64

typedef __attribute__((ext_vector_type(8))) short short8;
typedef __attribute__((ext_vector_type(4))) float f32x4;
typedef __attribute__((ext_vector_type(4))) unsigned short us4;

enum { MODE_SPLIT = 0, MODE_TRANS = 1, MODE_F32 = 2, MODE_FINAL = 3 };

__device__ __forceinline__ float b2f(unsigned short u) {
  union { unsigned int i; float f; } x;
  x.i = ((unsigned int)u) << 16;
  return x.f;
}
__device__ __forceinline__ unsigned short f2b(float f) {
  unsigned int u = __float_as_uint(f);
  unsigned int r = (u + 0x7FFFu + ((u >> 16) & 1u)) >> 16;
  return (unsigned short)r;
}

__device__ __forceinline__ void async_cp16(const unsigned short* g,
                                           unsigned short* l) {
  __builtin_amdgcn_global_load_lds(
      (const __attribute__((address_space(1))) void*)g,
      (__attribute__((address_space(3))) void*)l, 16, 0, 0);
}

// fp32 [rows][1024] -> bf16 [rows][2048] laid out [hi(1024) | lo(1024)]
__global__ __launch_bounds__(256) void split_hilo(const float* __restrict__ src,
                                                  unsigned short* __restrict__ dst,
                                                  int n4) {
  int g = blockIdx.x * 256 + threadIdx.x;
  if (g >= n4) return;
  const int e = g * 4;
  const int r = e >> 10;
  const int c = e & 1023;
  f32x4 v = *(const f32x4*)&src[e];
  us4 hi, lo;
#pragma unroll
  for (int i = 0; i < 4; ++i) {
    hi[i] = f2b(v[i]);
    lo[i] = f2b(v[i] - b2f(hi[i]));
  }
  *(us4*)&dst[(size_t)r * 2048 + c] = hi;
  *(us4*)&dst[(size_t)r * 2048 + 1024 + c] = lo;
}

// fp32 -> bf16 plain
__global__ __launch_bounds__(256) void cvt_bf16(const float* __restrict__ src,
                                                unsigned short* __restrict__ dst,
                                                int n4) {
  int g = blockIdx.x * 256 + threadIdx.x;
  if (g >= n4) return;
  f32x4 v = *(const f32x4*)&src[g * 4];
  us4 o;
#pragma unroll
  for (int i = 0; i < 4; ++i) o[i] = f2b(v[i]);
  *(us4*)&dst[(size_t)g * 4] = o;
}

// MODE_SPLIT: bf16 hi at [m][n], lo at [m][n+ldc/2]
// MODE_TRANS: bf16 at giT[batch][n][s] (batch=gm>>11, s=gm&2047; S=2048,C=1024)
// MODE_F32  : fp32 at [m][n]
// MODE_FINAL: fp32 (v + bias + resid[m][n])
template <int MODE>
__global__ __launch_bounds__(256, 2) void gemm_bt(
    const unsigned short* __restrict__ A, const unsigned short* __restrict__ B,
    void* __restrict__ Cout, const float* __restrict__ bias,
    const float* __restrict__ resid, int M, int N, int K, int lda, int ldb,
    int ldc, long long sA, long long sB, long long sC, int awrap, int awoff,
    int bwrap, int bwoff) {
  __shared__ __align__(16) unsigned short As[BM * BK];
  __shared__ __align__(16) unsigned short Bs[BN * BK];

  const int tid = threadIdx.x;
  const int l = tid & 63;
  const int w = tid >> 6;
  const int wm = w >> 1, wn = w & 1;
  const int ln = l & 15, lq = l >> 4;

  const int bm = blockIdx.y * BM;
  const int bn = blockIdx.x * BN;
  const unsigned short* Ab = A + (size_t)blockIdx.z * (size_t)sA;
  const unsigned short* Bb = B + (size_t)blockIdx.z * (size_t)sB;

  const int arow = tid >> 3;       // 0..31
  const int acol = (tid & 7) * 8;  // 16B per lane
  // LDS deposit: wave-uniform base + lane*16B => elem (it*2048 + w*512) + l*8
  // == row-major As[r*BK + acol] with r = it*32 + arow.  [m104/m108 contract]
  const int ldsbase = (tid & 0xC0) * 8;  // w*512 elements

  f32x4 acc[4][4];
#pragma unroll
  for (int i = 0; i < 4; ++i)
#pragma unroll
    for (int j = 0; j < 4; ++j) acc[i][j] = (f32x4){0.f, 0.f, 0.f, 0.f};

  for (int k0 = 0; k0 < K; k0 += BK) {
    const int ka = (k0 < awrap) ? k0 : k0 - awoff;
    const int kb = (k0 < bwrap) ? k0 : k0 - bwoff;
#pragma unroll
    for (int it = 0; it < 4; ++it) {
      const int r = it * 32 + arow;
      async_cp16(Ab + (size_t)(bm + r) * lda + ka + acol,
                 &As[it * 2048 + ldsbase]);
    }
#pragma unroll
    for (int it = 0; it < 4; ++it) {
      const int r = it * 32 + arow;
      async_cp16(Bb + (size_t)(bn + r) * ldb + kb + acol,
                 &Bs[it * 2048 + ldsbase]);
    }
    __syncthreads();  // vmcnt(0) drain + all waves issued

#pragma unroll
    for (int ks = 0; ks < 2; ++ks) {
      short8 a[4], b[4];
      const int kof = ks * 32 + lq * 8;
#pragma unroll
      for (int i = 0; i < 4; ++i)
        a[i] = *(const short8*)&As[(wm * 64 + i * 16 + ln) * BK + kof];
#pragma unroll
      for (int j = 0; j < 4; ++j)
        b[j] = *(const short8*)&Bs[(wn * 64 + j * 16 + ln) * BK + kof];
#pragma unroll
      for (int i = 0; i < 4; ++i)
#pragma unroll
        for (int j = 0; j < 4; ++j)
          acc[i][j] = __builtin_amdgcn_mfma_f32_16x16x32_bf16(a[i], b[j],
                                                              acc[i][j], 0, 0, 0);
    }
    __syncthreads();  // all reads done before next iter's cps overwrite
  }

  float* Cf = (float*)Cout + (size_t)blockIdx.z * (size_t)sC;
  unsigned short* Cb = (unsigned short*)Cout + (size_t)blockIdx.z * (size_t)sC;

  if constexpr (MODE == MODE_TRANS) {
#pragma unroll
    for (int i = 0; i < 4; ++i) {
      const int gm0 = bm + wm * 64 + i * 16 + lq * 4;
      const int bt = gm0 >> 11;
      const int sr = gm0 & 2047;
#pragma unroll
      for (int j = 0; j < 4; ++j) {
        const int gn = bn + wn * 64 + j * 16 + ln;
        const float bv2 = (bias != nullptr) ? bias[gn] : 0.f;
        us4 o;
#pragma unroll
        for (int r = 0; r < 4; ++r) o[r] = f2b(acc[i][j][r] + bv2);
        *(us4*)&Cb[(size_t)bt * 2097152 + (size_t)gn * 2048 + sr] = o;
      }
    }
  } else {
#pragma unroll
    for (int j = 0; j < 4; ++j) {
      const int gn = bn + wn * 64 + j * 16 + ln;
      const float bv2 = (bias != nullptr) ? bias[gn] : 0.f;
#pragma unroll
      for (int i = 0; i < 4; ++i) {
        const int gm0 = bm + wm * 64 + i * 16 + lq * 4;
#pragma unroll
        for (int r = 0; r < 4; ++r) {
          const int gm = gm0 + r;
          const float v = acc[i][j][r] + bv2;
          if constexpr (MODE == MODE_SPLIT) {
            unsigned short hi = f2b(v);
            Cb[(size_t)gm * ldc + gn] = hi;
            Cb[(size_t)gm * ldc + gn + (ldc >> 1)] = f2b(v - b2f(hi));
          } else if constexpr (MODE == MODE_F32) {
            Cf[(size_t)gm * ldc + gn] = v;
          } else if constexpr (MODE == MODE_FINAL) {
            const size_t idx = (size_t)gm * ldc + gn;
            Cf[idx] = v + resid[idx];
          }
        }
      }
    }
  }
}

// softmax over 2048 fp32 cols, scale 32; writes bf16 attn IN PLACE over the
// first half of the fp32 row (barriers order all reads before writes).
__global__ __launch_bounds__(256) void softmax_rows(float* __restrict__ logit) {
  const int row = blockIdx.x;
  float* L = logit + (size_t)row * 2048;
  unsigned short* O = (unsigned short*)L;
  const int t = threadIdx.x;
  __shared__ float red[8];

  f32x4 v0 = *(const f32x4*)&L[t * 4];
  f32x4 v1 = *(const f32x4*)&L[t * 4 + 1024];
  float m = fmaxf(fmaxf(fmaxf(v0[0], v0[1]), fmaxf(v0[2], v0[3])),
                  fmaxf(fmaxf(v1[0], v1[1]), fmaxf(v1[2], v1[3])));
  for (int o = 32; o; o >>= 1) m = fmaxf(m, __shfl_xor(m, o, 64));
  if ((t & 63) == 0) red[t >> 6] = m;
  __syncthreads();
  m = fmaxf(fmaxf(red[0], red[1]), fmaxf(red[2], red[3]));

  float e[8];
  float s = 0.f;
#pragma unroll
  for (int i = 0; i < 4; ++i) { e[i] = __expf(32.f * (v0[i] - m)); s += e[i]; }
#pragma unroll
  for (int i = 0; i < 4; ++i) { e[4 + i] = __expf(32.f * (v1[i] - m)); s += e[4 + i]; }
  for (int o = 32; o; o >>= 1) s += __shfl_xor(s, o, 64);
  if ((t & 63) == 0) red[4 + (t >> 6)] = s;
  __syncthreads();  // orders all row reads before any in-place write
  s = red[4] + red[5] + red[6] + red[7];
  const float inv = 1.f / s;
  us4 o0, o1;
#pragma unroll
  for (int i = 0; i < 4; ++i) { o0[i] = f2b(e[i] * inv); o1[i] = f2b(e[4 + i] * inv); }
  *(us4*)&O[t * 4] = o0;
  *(us4*)&O[t * 4 + 1024] = o1;
}

// LayerNorm(C=1024) + ReLU, fp32 in, fp32 g/b -> bf16 out
__global__ __launch_bounds__(256) void ln_relu(
    const float* __restrict__ X, const float* __restrict__ g,
    const float* __restrict__ b, unsigned short* __restrict__ H) {
  const int row = blockIdx.x;
  const float* x = X + (size_t)row * 1024;
  unsigned short* h = H + (size_t)row * 1024;
  const int t = threadIdx.x;
  __shared__ float red[8];
  f32x4 v = *(const f32x4*)&x[t * 4];
  float s = v[0] + v[1] + v[2] + v[3];
  float q = v[0] * v[0] + v[1] * v[1] + v[2] * v[2] + v[3] * v[3];
  for (int o = 32; o; o >>= 1) {
    s += __shfl_xor(s, o, 64);
    q += __shfl_xor(q, o, 64);
  }
  if ((t & 63) == 0) { red[t >> 6] = s; red[4 + (t >> 6)] = q; }
  __syncthreads();
  s = red[0] + red[1] + red[2] + red[3];
  q = red[4] + red[5] + red[6] + red[7];
  const float mean = s * (1.f / 1024.f);
  const float var = q * (1.f / 1024.f) - mean * mean;
  const float rstd = rsqrtf(var + 1e-5f);
  us4 o;
#pragma unroll
  for (int i = 0; i < 4; ++i) {
    const int c = t * 4 + i;
    const float y = (v[i] - mean) * rstd * g[c] + b[c];
    o[i] = f2b(fmaxf(y, 0.f));
  }
  *(us4*)&h[t * 4] = o;
}

extern "C" void kernel_launch(void* const* d_in, const int* in_sizes, int n_in,
                              void* d_out, int out_size, void* d_ws,
                              size_t ws_size, hipStream_t stream) {
  const float* x = (const float*)d_in[0];
  const float* lfb = (const float*)d_in[1];
  const float* th_w = (const float*)d_in[2];
  const float* th_b = (const float*)d_in[3];
  const float* ph_w = (const float*)d_in[4];
  const float* ph_b = (const float*)d_in[5];
  const float* gi_w = (const float*)d_in[6];
  const float* gi_b = (const float*)d_in[7];
  const float* lng = (const float*)d_in[8];
  const float* lnb = (const float*)d_in[9];
  const float* fc_w = (const float*)d_in[10];
  const float* fc_b = (const float*)d_in[11];
  float* outf = (float*)d_out;
  char* ws = (char*)d_ws;

  const size_t MB = 1048576;
  // Grouped layout: nb*28 MiB + 12 MiB weights. Fallback: T-chunked, 32 MiB +
  // Tc*14 KiB.
  int nb = 0;
  for (int cand = 8; cand >= 1; cand >>= 1)
    if ((size_t)cand * 28 * MB + 12 * MB <= ws_size) { nb = cand; break; }
  int Tc = 1024;
  if (nb == 0) {
    nb = 1;
    Tc = 512;
    while (Tc > 128 && 32 * MB + (size_t)Tc * 14336 > ws_size) Tc >>= 1;
  }

  char* wbuf = (Tc == 1024) ? (ws + (size_t)nb * 28 * MB) : (ws + 20 * MB);
  unsigned short* thw = (unsigned short*)(wbuf);
  unsigned short* phw = (unsigned short*)(wbuf + 4 * MB);
  unsigned short* giw = (unsigned short*)(wbuf + 8 * MB);
  unsigned short* fcw = (unsigned short*)(wbuf + 10 * MB);

  dim3 blk(256);
  // weights: split th_w/ph_w hi/lo, cvt gi_w/fc_w (1M elems each -> 256K x4)
  split_hilo<<<dim3(1024), blk, 0, stream>>>(th_w, thw, 262144);
  split_hilo<<<dim3(1024), blk, 0, stream>>>(ph_w, phw, 262144);
  cvt_bf16<<<dim3(1024), blk, 0, stream>>>(gi_w, giw, 262144);
  cvt_bf16<<<dim3(1024), blk, 0, stream>>>(fc_w, fcw, 262144);

  for (int b0 = 0; b0 < 8; b0 += nb) {
    unsigned short *xs, *ls, *theta, *phi, *giT;
    float* logit;
    if (Tc == 1024) {
      xs    = (unsigned short*)(ws);                        // [nb*1024][2048]
      ls    = (unsigned short*)(ws + (size_t)nb * 4 * MB);  // [nb*2048][2048]
      theta = (unsigned short*)(ws + (size_t)nb * 12 * MB); // [nb*1024][2048]
      phi   = (unsigned short*)(ws + (size_t)nb * 16 * MB); // [nb*2048][2048]
      giT   = (unsigned short*)(ws + (size_t)nb * 24 * MB); // [nb][1024][2048]
      logit = (float*)(ws);  // reuses xs+ls (dead after theta/phi/gi GEMMs)
    } else {
      ls    = (unsigned short*)(ws);                        // 8 MiB
      phi   = (unsigned short*)(ws + 8 * MB);               // 8 MiB
      giT   = (unsigned short*)(ws + 16 * MB);              // 4 MiB
      xs    = (unsigned short*)(ws + 32 * MB);              // Tc*2 KiB
      theta = (unsigned short*)(ws + 32 * MB + (size_t)Tc * 2048);   // Tc*4 KiB
      logit = (float*)(ws + 32 * MB + (size_t)Tc * 6144);   // Tc*8 KiB
    }
    float* outp = (float*)phi;            // phi dead after QK^T
    unsigned short* h = theta;            // theta dead after QK^T
    unsigned short* attn = (unsigned short*)logit;  // in place, stride 4096

    const float* xb = x + (size_t)b0 * 1048576;
    const float* lfbb = lfb + (size_t)b0 * 2097152;
    float* ob = outf + (size_t)b0 * 1048576;
    const int Ms = nb * 2048;
    const int Mq = (Tc == 1024) ? 1024 : Tc;  // per-z query rows

    // split lfb -> ls
    split_hilo<<<dim3(Ms), blk, 0, stream>>>(lfbb, ls, Ms * 256);
    // phi = [lh,ll,lh].[wh,wh,wl] + ph_b -> hi/lo    [Ms][2048]
    gemm_bt<MODE_SPLIT><<<dim3(8, Ms / 128, 1), blk, 0, stream>>>(
        ls, phw, phi, ph_b, nullptr, Ms, 1024, 3072, 2048, 2048, 2048,
        0, 0, 0, 2048, 2048, 1024, 1024);
    // giT[b][c][s] = (lfb_h @ gi_w^T + gi_b)^T  (plain bf16, K=1024)
    gemm_bt<MODE_TRANS><<<dim3(8, Ms / 128, 1), blk, 0, stream>>>(
        ls, giw, giT, gi_b, nullptr, Ms, 1024, 1024, 2048, 1024, 2048,
        0, 0, 0, 1024, 0, 1024, 0);

    for (int t0 = 0; t0 < 1024; t0 += Tc) {
      const int rows = nb * Tc;
      const float* xq = xb + (size_t)t0 * 1024;
      float* oq = ob + (size_t)t0 * 1024;

      // split x chunk -> xs
      split_hilo<<<dim3(rows), blk, 0, stream>>>(xq, xs, rows * 256);
      // theta = [xh,xl,xh].[wh,wh,wl] + th_b -> hi/lo   [rows][2048]
      gemm_bt<MODE_SPLIT><<<dim3(8, rows / 128, 1), blk, 0, stream>>>(
          xs, thw, theta, th_b, nullptr, rows, 1024, 3072, 2048, 2048, 2048,
          0, 0, 0, 2048, 2048, 1024, 1024);
      // logits = [th,tl,th].[ph,ph,pl]  (K=3072), fp32
      gemm_bt<MODE_F32><<<dim3(16, Mq / 128, nb), blk, 0, stream>>>(
          theta, phi, logit, nullptr, nullptr, Mq, 2048, 3072, 2048, 2048,
          2048, 2097152LL, 4194304LL, 2097152LL, 2048, 2048, 1024, 1024);
      // attn = softmax(32*logits), bf16 in place (row stride 4096 shorts)
      softmax_rows<<<dim3(rows), blk, 0, stream>>>(logit);
      // outp = attn @ giT^T (fp32)
      gemm_bt<MODE_F32><<<dim3(8, Mq / 128, nb), blk, 0, stream>>>(
          attn, giT, outp, nullptr, nullptr, Mq, 1024, 2048, 4096, 2048, 1024,
          4194304LL, 2097152LL, 1048576LL, 2048, 0, 2048, 0);
      // h = relu(LN(outp))
      ln_relu<<<dim3(rows), blk, 0, stream>>>(outp, lng, lnb, h);
      // out = h @ fc_w^T + fc_b + x   (fp32 out + fp32 resid)
      gemm_bt<MODE_FINAL><<<dim3(8, rows / 128, 1), blk, 0, stream>>>(
          h, fcw, oq, fc_b, xq, rows, 1024, 1024, 1024, 1024, 1024,
          0, 0, 0, 1024, 0, 1024, 0);
    }
  }
}

// Round 6
// 680.416 us; speedup vs baseline: 1.1467x; 1.1467x over previous
//
#include <hip/hip_runtime.h>

// NLBlock fused pipeline for MI355X (gfx950). ALL I/O IS FP32 (per reference).
// Internally: bf16 MFMA GEMMs; split-precision (hi/lo bf16) for x,lfb,th_w,ph_w,
// theta,phi so the x32-scaled softmax logits stay accurate.
// GEMM form: C[m][n] = sum_k A[m][k]*B[n][k] (+bias). 128x128x64 tile, 4 waves.
// R6: XOR-swizzled LDS layout (chunk pc of row r holds k-chunk pc^(r&7)) to kill
// the 16-lanes-per-bank-quad conflict in fragment ds_read_b128 (3.775e7 conflicts
// in R4/R5, both staging variants identical => reads are the limiter).

#define BM 128
#define BN 128
#define BK 64

typedef __attribute__((ext_vector_type(8))) short short8;
typedef __attribute__((ext_vector_type(4))) float f32x4;
typedef __attribute__((ext_vector_type(4))) unsigned short us4;

enum { MODE_SPLIT = 0, MODE_TRANS = 1, MODE_F32 = 2, MODE_FINAL = 3 };

__device__ __forceinline__ float b2f(unsigned short u) {
  union { unsigned int i; float f; } x;
  x.i = ((unsigned int)u) << 16;
  return x.f;
}
__device__ __forceinline__ unsigned short f2b(float f) {
  unsigned int u = __float_as_uint(f);
  unsigned int r = (u + 0x7FFFu + ((u >> 16) & 1u)) >> 16;
  return (unsigned short)r;
}

__device__ __forceinline__ void async_cp16(const unsigned short* g,
                                           unsigned short* l) {
  __builtin_amdgcn_global_load_lds(
      (const __attribute__((address_space(1))) void*)g,
      (__attribute__((address_space(3))) void*)l, 16, 0, 0);
}

// fp32 [rows][1024] -> bf16 [rows][2048] laid out [hi(1024) | lo(1024)]
__global__ __launch_bounds__(256) void split_hilo(const float* __restrict__ src,
                                                  unsigned short* __restrict__ dst,
                                                  int n4) {
  int g = blockIdx.x * 256 + threadIdx.x;
  if (g >= n4) return;
  const int e = g * 4;
  const int r = e >> 10;
  const int c = e & 1023;
  f32x4 v = *(const f32x4*)&src[e];
  us4 hi, lo;
#pragma unroll
  for (int i = 0; i < 4; ++i) {
    hi[i] = f2b(v[i]);
    lo[i] = f2b(v[i] - b2f(hi[i]));
  }
  *(us4*)&dst[(size_t)r * 2048 + c] = hi;
  *(us4*)&dst[(size_t)r * 2048 + 1024 + c] = lo;
}

// fp32 -> bf16 plain
__global__ __launch_bounds__(256) void cvt_bf16(const float* __restrict__ src,
                                                unsigned short* __restrict__ dst,
                                                int n4) {
  int g = blockIdx.x * 256 + threadIdx.x;
  if (g >= n4) return;
  f32x4 v = *(const f32x4*)&src[g * 4];
  us4 o;
#pragma unroll
  for (int i = 0; i < 4; ++i) o[i] = f2b(v[i]);
  *(us4*)&dst[(size_t)g * 4] = o;
}

// MODE_SPLIT: bf16 hi at [m][n], lo at [m][n+ldc/2]
// MODE_TRANS: bf16 at giT[batch][n][s] (batch=gm>>11, s=gm&2047; S=2048,C=1024)
// MODE_F32  : fp32 at [m][n]
// MODE_FINAL: fp32 (v + bias + resid[m][n])
template <int MODE>
__global__ __launch_bounds__(256, 2) void gemm_bt(
    const unsigned short* __restrict__ A, const unsigned short* __restrict__ B,
    void* __restrict__ Cout, const float* __restrict__ bias,
    const float* __restrict__ resid, int M, int N, int K, int lda, int ldb,
    int ldc, long long sA, long long sB, long long sC, int awrap, int awoff,
    int bwrap, int bwoff) {
  __shared__ __align__(16) unsigned short As[BM * BK];
  __shared__ __align__(16) unsigned short Bs[BN * BK];

  const int tid = threadIdx.x;
  const int l = tid & 63;
  const int w = tid >> 6;
  const int wm = w >> 1, wn = w & 1;
  const int ln = l & 15, lq = l >> 4;

  const int bm = blockIdx.y * BM;
  const int bn = blockIdx.x * BN;
  const unsigned short* Ab = A + (size_t)blockIdx.z * (size_t)sA;
  const unsigned short* Bb = B + (size_t)blockIdx.z * (size_t)sB;

  const int arow = tid >> 3;  // 0..31 (global row within 32-row group)
  // Swizzled global fetch: lane (rr=l>>3, cc=l&7) fetches k-chunk cc^rr of its
  // row. Deposit slot is forced to base+lane*16B, so LDS chunk pc of row r
  // holds k-chunk pc^(r&7).  [m104/m108 contract]
  const int acol = (((tid & 7) ^ ((tid >> 3) & 7)) * 8);
  const int ldsbase = (tid & 0xC0) * 8;  // w*512 elements (8 rows/wave/issue)

  f32x4 acc[4][4];
#pragma unroll
  for (int i = 0; i < 4; ++i)
#pragma unroll
    for (int j = 0; j < 4; ++j) acc[i][j] = (f32x4){0.f, 0.f, 0.f, 0.f};

  const int sw = ln & 7;  // row&7 for all fragment rows (bases are 8-aligned)

  for (int k0 = 0; k0 < K; k0 += BK) {
    const int ka = (k0 < awrap) ? k0 : k0 - awoff;
    const int kb = (k0 < bwrap) ? k0 : k0 - bwoff;
#pragma unroll
    for (int it = 0; it < 4; ++it) {
      const int r = it * 32 + arow;
      async_cp16(Ab + (size_t)(bm + r) * lda + ka + acol,
                 &As[it * 2048 + ldsbase]);
    }
#pragma unroll
    for (int it = 0; it < 4; ++it) {
      const int r = it * 32 + arow;
      async_cp16(Bb + (size_t)(bn + r) * ldb + kb + acol,
                 &Bs[it * 2048 + ldsbase]);
    }
    __syncthreads();  // vmcnt(0) drain + all waves issued

#pragma unroll
    for (int ks = 0; ks < 2; ++ks) {
      short8 a[4], b[4];
      const int kof = ((ks * 4 + lq) ^ sw) * 8;  // swizzled k-offset (elems)
#pragma unroll
      for (int i = 0; i < 4; ++i)
        a[i] = *(const short8*)&As[(wm * 64 + i * 16 + ln) * BK + kof];
#pragma unroll
      for (int j = 0; j < 4; ++j)
        b[j] = *(const short8*)&Bs[(wn * 64 + j * 16 + ln) * BK + kof];
#pragma unroll
      for (int i = 0; i < 4; ++i)
#pragma unroll
        for (int j = 0; j < 4; ++j)
          acc[i][j] = __builtin_amdgcn_mfma_f32_16x16x32_bf16(a[i], b[j],
                                                              acc[i][j], 0, 0, 0);
    }
    __syncthreads();  // all reads done before next iter's cps overwrite
  }

  float* Cf = (float*)Cout + (size_t)blockIdx.z * (size_t)sC;
  unsigned short* Cb = (unsigned short*)Cout + (size_t)blockIdx.z * (size_t)sC;

  if constexpr (MODE == MODE_TRANS) {
#pragma unroll
    for (int i = 0; i < 4; ++i) {
      const int gm0 = bm + wm * 64 + i * 16 + lq * 4;
      const int bt = gm0 >> 11;
      const int sr = gm0 & 2047;
#pragma unroll
      for (int j = 0; j < 4; ++j) {
        const int gn = bn + wn * 64 + j * 16 + ln;
        const float bv2 = (bias != nullptr) ? bias[gn] : 0.f;
        us4 o;
#pragma unroll
        for (int r = 0; r < 4; ++r) o[r] = f2b(acc[i][j][r] + bv2);
        *(us4*)&Cb[(size_t)bt * 2097152 + (size_t)gn * 2048 + sr] = o;
      }
    }
  } else {
#pragma unroll
    for (int j = 0; j < 4; ++j) {
      const int gn = bn + wn * 64 + j * 16 + ln;
      const float bv2 = (bias != nullptr) ? bias[gn] : 0.f;
#pragma unroll
      for (int i = 0; i < 4; ++i) {
        const int gm0 = bm + wm * 64 + i * 16 + lq * 4;
#pragma unroll
        for (int r = 0; r < 4; ++r) {
          const int gm = gm0 + r;
          const float v = acc[i][j][r] + bv2;
          if constexpr (MODE == MODE_SPLIT) {
            unsigned short hi = f2b(v);
            Cb[(size_t)gm * ldc + gn] = hi;
            Cb[(size_t)gm * ldc + gn + (ldc >> 1)] = f2b(v - b2f(hi));
          } else if constexpr (MODE == MODE_F32) {
            Cf[(size_t)gm * ldc + gn] = v;
          } else if constexpr (MODE == MODE_FINAL) {
            const size_t idx = (size_t)gm * ldc + gn;
            Cf[idx] = v + resid[idx];
          }
        }
      }
    }
  }
}

// softmax over 2048 fp32 cols, scale 32; writes bf16 attn IN PLACE over the
// first half of the fp32 row (barriers order all reads before writes).
__global__ __launch_bounds__(256) void softmax_rows(float* __restrict__ logit) {
  const int row = blockIdx.x;
  float* L = logit + (size_t)row * 2048;
  unsigned short* O = (unsigned short*)L;
  const int t = threadIdx.x;
  __shared__ float red[8];

  f32x4 v0 = *(const f32x4*)&L[t * 4];
  f32x4 v1 = *(const f32x4*)&L[t * 4 + 1024];
  float m = fmaxf(fmaxf(fmaxf(v0[0], v0[1]), fmaxf(v0[2], v0[3])),
                  fmaxf(fmaxf(v1[0], v1[1]), fmaxf(v1[2], v1[3])));
  for (int o = 32; o; o >>= 1) m = fmaxf(m, __shfl_xor(m, o, 64));
  if ((t & 63) == 0) red[t >> 6] = m;
  __syncthreads();
  m = fmaxf(fmaxf(red[0], red[1]), fmaxf(red[2], red[3]));

  float e[8];
  float s = 0.f;
#pragma unroll
  for (int i = 0; i < 4; ++i) { e[i] = __expf(32.f * (v0[i] - m)); s += e[i]; }
#pragma unroll
  for (int i = 0; i < 4; ++i) { e[4 + i] = __expf(32.f * (v1[i] - m)); s += e[4 + i]; }
  for (int o = 32; o; o >>= 1) s += __shfl_xor(s, o, 64);
  if ((t & 63) == 0) red[4 + (t >> 6)] = s;
  __syncthreads();  // orders all row reads before any in-place write
  s = red[4] + red[5] + red[6] + red[7];
  const float inv = 1.f / s;
  us4 o0, o1;
#pragma unroll
  for (int i = 0; i < 4; ++i) { o0[i] = f2b(e[i] * inv); o1[i] = f2b(e[4 + i] * inv); }
  *(us4*)&O[t * 4] = o0;
  *(us4*)&O[t * 4 + 1024] = o1;
}

// LayerNorm(C=1024) + ReLU, fp32 in, fp32 g/b -> bf16 out
__global__ __launch_bounds__(256) void ln_relu(
    const float* __restrict__ X, const float* __restrict__ g,
    const float* __restrict__ b, unsigned short* __restrict__ H) {
  const int row = blockIdx.x;
  const float* x = X + (size_t)row * 1024;
  unsigned short* h = H + (size_t)row * 1024;
  const int t = threadIdx.x;
  __shared__ float red[8];
  f32x4 v = *(const f32x4*)&x[t * 4];
  float s = v[0] + v[1] + v[2] + v[3];
  float q = v[0] * v[0] + v[1] * v[1] + v[2] * v[2] + v[3] * v[3];
  for (int o = 32; o; o >>= 1) {
    s += __shfl_xor(s, o, 64);
    q += __shfl_xor(q, o, 64);
  }
  if ((t & 63) == 0) { red[t >> 6] = s; red[4 + (t >> 6)] = q; }
  __syncthreads();
  s = red[0] + red[1] + red[2] + red[3];
  q = red[4] + red[5] + red[6] + red[7];
  const float mean = s * (1.f / 1024.f);
  const float var = q * (1.f / 1024.f) - mean * mean;
  const float rstd = rsqrtf(var + 1e-5f);
  us4 o;
#pragma unroll
  for (int i = 0; i < 4; ++i) {
    const int c = t * 4 + i;
    const float y = (v[i] - mean) * rstd * g[c] + b[c];
    o[i] = f2b(fmaxf(y, 0.f));
  }
  *(us4*)&h[t * 4] = o;
}

extern "C" void kernel_launch(void* const* d_in, const int* in_sizes, int n_in,
                              void* d_out, int out_size, void* d_ws,
                              size_t ws_size, hipStream_t stream) {
  const float* x = (const float*)d_in[0];
  const float* lfb = (const float*)d_in[1];
  const float* th_w = (const float*)d_in[2];
  const float* th_b = (const float*)d_in[3];
  const float* ph_w = (const float*)d_in[4];
  const float* ph_b = (const float*)d_in[5];
  const float* gi_w = (const float*)d_in[6];
  const float* gi_b = (const float*)d_in[7];
  const float* lng = (const float*)d_in[8];
  const float* lnb = (const float*)d_in[9];
  const float* fc_w = (const float*)d_in[10];
  const float* fc_b = (const float*)d_in[11];
  float* outf = (float*)d_out;
  char* ws = (char*)d_ws;

  const size_t MB = 1048576;
  // Grouped layout: nb*28 MiB + 12 MiB weights. Fallback: T-chunked, 32 MiB +
  // Tc*14 KiB.
  int nb = 0;
  for (int cand = 8; cand >= 1; cand >>= 1)
    if ((size_t)cand * 28 * MB + 12 * MB <= ws_size) { nb = cand; break; }
  int Tc = 1024;
  if (nb == 0) {
    nb = 1;
    Tc = 512;
    while (Tc > 128 && 32 * MB + (size_t)Tc * 14336 > ws_size) Tc >>= 1;
  }

  char* wbuf = (Tc == 1024) ? (ws + (size_t)nb * 28 * MB) : (ws + 20 * MB);
  unsigned short* thw = (unsigned short*)(wbuf);
  unsigned short* phw = (unsigned short*)(wbuf + 4 * MB);
  unsigned short* giw = (unsigned short*)(wbuf + 8 * MB);
  unsigned short* fcw = (unsigned short*)(wbuf + 10 * MB);

  dim3 blk(256);
  // weights: split th_w/ph_w hi/lo, cvt gi_w/fc_w (1M elems each -> 256K x4)
  split_hilo<<<dim3(1024), blk, 0, stream>>>(th_w, thw, 262144);
  split_hilo<<<dim3(1024), blk, 0, stream>>>(ph_w, phw, 262144);
  cvt_bf16<<<dim3(1024), blk, 0, stream>>>(gi_w, giw, 262144);
  cvt_bf16<<<dim3(1024), blk, 0, stream>>>(fc_w, fcw, 262144);

  for (int b0 = 0; b0 < 8; b0 += nb) {
    unsigned short *xs, *ls, *theta, *phi, *giT;
    float* logit;
    if (Tc == 1024) {
      xs    = (unsigned short*)(ws);                        // [nb*1024][2048]
      ls    = (unsigned short*)(ws + (size_t)nb * 4 * MB);  // [nb*2048][2048]
      theta = (unsigned short*)(ws + (size_t)nb * 12 * MB); // [nb*1024][2048]
      phi   = (unsigned short*)(ws + (size_t)nb * 16 * MB); // [nb*2048][2048]
      giT   = (unsigned short*)(ws + (size_t)nb * 24 * MB); // [nb][1024][2048]
      logit = (float*)(ws);  // reuses xs+ls (dead after theta/phi/gi GEMMs)
    } else {
      ls    = (unsigned short*)(ws);                        // 8 MiB
      phi   = (unsigned short*)(ws + 8 * MB);               // 8 MiB
      giT   = (unsigned short*)(ws + 16 * MB);              // 4 MiB
      xs    = (unsigned short*)(ws + 32 * MB);              // Tc*2 KiB
      theta = (unsigned short*)(ws + 32 * MB + (size_t)Tc * 2048);   // Tc*4 KiB
      logit = (float*)(ws + 32 * MB + (size_t)Tc * 6144);   // Tc*8 KiB
    }
    float* outp = (float*)phi;            // phi dead after QK^T
    unsigned short* h = theta;            // theta dead after QK^T
    unsigned short* attn = (unsigned short*)logit;  // in place, stride 4096

    const float* xb = x + (size_t)b0 * 1048576;
    const float* lfbb = lfb + (size_t)b0 * 2097152;
    float* ob = outf + (size_t)b0 * 1048576;
    const int Ms = nb * 2048;
    const int Mq = (Tc == 1024) ? 1024 : Tc;  // per-z query rows

    // split lfb -> ls
    split_hilo<<<dim3(Ms), blk, 0, stream>>>(lfbb, ls, Ms * 256);
    // phi = [lh,ll,lh].[wh,wh,wl] + ph_b -> hi/lo    [Ms][2048]
    gemm_bt<MODE_SPLIT><<<dim3(8, Ms / 128, 1), blk, 0, stream>>>(
        ls, phw, phi, ph_b, nullptr, Ms, 1024, 3072, 2048, 2048, 2048,
        0, 0, 0, 2048, 2048, 1024, 1024);
    // giT[b][c][s] = (lfb_h @ gi_w^T + gi_b)^T  (plain bf16, K=1024)
    gemm_bt<MODE_TRANS><<<dim3(8, Ms / 128, 1), blk, 0, stream>>>(
        ls, giw, giT, gi_b, nullptr, Ms, 1024, 1024, 2048, 1024, 2048,
        0, 0, 0, 1024, 0, 1024, 0);

    for (int t0 = 0; t0 < 1024; t0 += Tc) {
      const int rows = nb * Tc;
      const float* xq = xb + (size_t)t0 * 1024;
      float* oq = ob + (size_t)t0 * 1024;

      // split x chunk -> xs
      split_hilo<<<dim3(rows), blk, 0, stream>>>(xq, xs, rows * 256);
      // theta = [xh,xl,xh].[wh,wh,wl] + th_b -> hi/lo   [rows][2048]
      gemm_bt<MODE_SPLIT><<<dim3(8, rows / 128, 1), blk, 0, stream>>>(
          xs, thw, theta, th_b, nullptr, rows, 1024, 3072, 2048, 2048, 2048,
          0, 0, 0, 2048, 2048, 1024, 1024);
      // logits = [th,tl,th].[ph,ph,pl]  (K=3072), fp32
      gemm_bt<MODE_F32><<<dim3(16, Mq / 128, nb), blk, 0, stream>>>(
          theta, phi, logit, nullptr, nullptr, Mq, 2048, 3072, 2048, 2048,
          2048, 2097152LL, 4194304LL, 2097152LL, 2048, 2048, 1024, 1024);
      // attn = softmax(32*logits), bf16 in place (row stride 4096 shorts)
      softmax_rows<<<dim3(rows), blk, 0, stream>>>(logit);
      // outp = attn @ giT^T (fp32)
      gemm_bt<MODE_F32><<<dim3(8, Mq / 128, nb), blk, 0, stream>>>(
          attn, giT, outp, nullptr, nullptr, Mq, 1024, 2048, 4096, 2048, 1024,
          4194304LL, 2097152LL, 1048576LL, 2048, 0, 2048, 0);
      // h = relu(LN(outp))
      ln_relu<<<dim3(rows), blk, 0, stream>>>(outp, lng, lnb, h);
      // out = h @ fc_w^T + fc_b + x   (fp32 out + fp32 resid)
      gemm_bt<MODE_FINAL><<<dim3(8, rows / 128, 1), blk, 0, stream>>>(
          h, fcw, oq, fc_b, xq, rows, 1024, 1024, 1024, 1024, 1024,
          0, 0, 0, 1024, 0, 1024, 0);
    }
  }
}